// Round 10
// baseline (215.196 us; speedup 1.0000x reference)
//
#include <hip/hip_runtime.h>
#include <hip/hip_bf16.h>
#include <math.h>

typedef unsigned short u16;
typedef __attribute__((ext_vector_type(8))) __bf16 bf16x8;
typedef __attribute__((ext_vector_type(4))) float f32x4;
typedef __attribute__((ext_vector_type(8))) unsigned short u16x8;
typedef __attribute__((ext_vector_type(4))) unsigned int u32x4;

// ---------- helpers ----------
__device__ __forceinline__ u16 f2bf(float f) {
  union { float f; unsigned u; } x; x.f = f;
  unsigned r = x.u + 0x7fffu + ((x.u >> 16) & 1u);   // RNE
  return (u16)(r >> 16);
}

__device__ __forceinline__ void gload16(const u16* g, u16* l) {
  __builtin_amdgcn_global_load_lds(
      (const __attribute__((address_space(1))) void*)g,
      (__attribute__((address_space(3))) void*)l, 16, 0, 0);
}

#define MFMA16(a, b, c) __builtin_amdgcn_mfma_f32_16x16x32_bf16((a), (b), (c), 0, 0, 0)

// Q pre-scale: 1/sqrt(64) * log2(e)  (softmax done in exp2 domain)
#define QSCALE 0.18033688011112043f

// ---------- merged cast fp32 -> bf16 (x, Wqkv, Wo in one launch) ----------
__global__ __launch_bounds__(256) void cast_all_kernel(
    const float* __restrict__ x, const float* __restrict__ wqkv,
    const float* __restrict__ wo, u16* __restrict__ xb,
    u16* __restrict__ wqb, u16* __restrict__ wob) {
  int i = blockIdx.x * 256 + threadIdx.x;   // in float4 units
  const float* src; u16* dst;
  if (i < 1048576)      { src = x;    dst = xb;  }
  else if (i < 1835008) { src = wqkv; dst = wqb; i -= 1048576; }
  else                  { src = wo;   dst = wob; i -= 1835008; }
  f32x4 v = *(const f32x4*)(src + (size_t)i * 4);
  u16 o0 = f2bf(v[0]), o1 = f2bf(v[1]), o2 = f2bf(v[2]), o3 = f2bf(v[3]);
  unsigned lo = (unsigned)o0 | ((unsigned)o1 << 16);
  unsigned hi = (unsigned)o2 | ((unsigned)o3 << 16);
  ((unsigned*)dst)[(size_t)i * 2] = lo;
  ((unsigned*)dst)[(size_t)i * 2 + 1] = hi;
}

// ---------- shared 128x128 / BK=64 bf16 GEMM main loop (C = A * B^T) ----------
__device__ __forceinline__ void gemm_bt_128(
    const u16* __restrict__ A, const u16* __restrict__ B, int K, int m0, int n0,
    u16* As, u16* Bs, f32x4 acc[4][4]) {
  const int tid = threadIdx.x;
  const int lane = tid & 63;
  const int wr = tid >> 7;
  const int wc = (tid >> 6) & 1;
  for (int k0 = 0; k0 < K; k0 += 64) {
    #pragma unroll
    for (int it = 0; it < 4; ++it) {
      int c = it * 256 + tid;
      int row = c >> 3;
      int ko = (c & 7) << 3;
      gload16(A + (size_t)(m0 + row) * K + (k0 + ko), As + c * 8);
      gload16(B + (size_t)(n0 + row) * K + (k0 + ko), Bs + c * 8);
    }
    __syncthreads();
    #pragma unroll
    for (int kk = 0; kk < 2; ++kk) {
      bf16x8 a[4], b[4];
      #pragma unroll
      for (int m = 0; m < 4; ++m)
        a[m] = *(const bf16x8*)(As + ((wr * 64 + m * 16 + (lane & 15)) * 64 +
                                      kk * 32 + ((lane >> 4) << 3)));
      #pragma unroll
      for (int n = 0; n < 4; ++n)
        b[n] = *(const bf16x8*)(Bs + ((wc * 64 + n * 16 + (lane & 15)) * 64 +
                                      kk * 32 + ((lane >> 4) << 3)));
      #pragma unroll
      for (int m = 0; m < 4; ++m)
        #pragma unroll
        for (int n = 0; n < 4; ++n)
          acc[m][n] = MFMA16(a[m], b[n], acc[m][n]);
    }
    __syncthreads();
  }
}

// ---------- GEMM1: qkv = x @ Wqkv^T + b; Q,K per-head [q][d]; V per-head [d][q] ----------
__global__ __launch_bounds__(256) void gemm_qkv_kernel(
    const u16* __restrict__ X, const u16* __restrict__ W, const float* __restrict__ bias,
    u16* __restrict__ Qb, u16* __restrict__ Kb, u16* __restrict__ VTb) {
  __shared__ __align__(16) u16 As[128 * 64];
  __shared__ __align__(16) u16 Bs[128 * 64];
  f32x4 acc[4][4];
  #pragma unroll
  for (int m = 0; m < 4; ++m)
    #pragma unroll
    for (int n = 0; n < 4; ++n) acc[m][n] = (f32x4){0.f, 0.f, 0.f, 0.f};
  const int m0 = blockIdx.y * 128;
  const int n0 = blockIdx.x * 128;
  gemm_bt_128(X, W, 1024, m0, n0, As, Bs, acc);
  const int lane = threadIdx.x & 63;
  const int wr = threadIdx.x >> 7, wc = (threadIdx.x >> 6) & 1;
  #pragma unroll
  for (int m = 0; m < 4; ++m) {
    #pragma unroll
    for (int n = 0; n < 4; ++n) {
      #pragma unroll
      for (int j = 0; j < 4; ++j) {
        int row = m0 + wr * 64 + m * 16 + ((lane >> 4) << 2) + j;
        int col = n0 + wc * 64 + n * 16 + (lane & 15);
        float v = acc[m][n][j] + bias[col];
        int which = col >> 10;
        int rem = col & 1023;
        int h = rem >> 6, d = rem & 63;
        int bb = row >> 11, q = row & 2047;
        int hh = bb * 16 + h;
        if (which == 0) {
          Qb[((size_t)hh * 2048 + q) * 64 + d] = f2bf(v * QSCALE);
        } else if (which == 1) {
          Kb[((size_t)hh * 2048 + q) * 64 + d] = f2bf(v);
        } else {
          VTb[((size_t)hh * 64 + d) * 2048 + q] = f2bf(v);   // transposed
        }
      }
    }
  }
}

// ---------- GEMM2: out = attn @ Wo^T + b (fp32 out), 64x128 tile ----------
__global__ __launch_bounds__(256) void gemm_out_kernel(
    const u16* __restrict__ Ain, const u16* __restrict__ W, const float* __restrict__ bias,
    float* __restrict__ out) {
  __shared__ __align__(16) u16 As[64 * 64];
  __shared__ __align__(16) u16 Bs[128 * 64];
  const int tid = threadIdx.x;
  const int lane = tid & 63;
  const int wc = tid >> 6;                 // wave -> 32-col group
  const int m0 = blockIdx.y * 64;
  const int n0 = blockIdx.x * 128;
  f32x4 acc[4][2] = {};
  for (int k0 = 0; k0 < 1024; k0 += 64) {
    #pragma unroll
    for (int it = 0; it < 2; ++it) {
      int c = it * 256 + tid;
      gload16(Ain + (size_t)(m0 + (c >> 3)) * 1024 + k0 + ((c & 7) << 3), As + c * 8);
    }
    #pragma unroll
    for (int it = 0; it < 4; ++it) {
      int c = it * 256 + tid;
      gload16(W + (size_t)(n0 + (c >> 3)) * 1024 + k0 + ((c & 7) << 3), Bs + c * 8);
    }
    __syncthreads();
    #pragma unroll
    for (int kk = 0; kk < 2; ++kk) {
      bf16x8 a[4], b[2];
      #pragma unroll
      for (int m = 0; m < 4; ++m)
        a[m] = *(const bf16x8*)(As + ((m * 16 + (lane & 15)) * 64 +
                                      kk * 32 + ((lane >> 4) << 3)));
      #pragma unroll
      for (int n = 0; n < 2; ++n)
        b[n] = *(const bf16x8*)(Bs + ((wc * 32 + n * 16 + (lane & 15)) * 64 +
                                      kk * 32 + ((lane >> 4) << 3)));
      #pragma unroll
      for (int m = 0; m < 4; ++m)
        #pragma unroll
        for (int n = 0; n < 2; ++n)
          acc[m][n] = MFMA16(a[m], b[n], acc[m][n]);
    }
    __syncthreads();
  }
  #pragma unroll
  for (int m = 0; m < 4; ++m)
    #pragma unroll
    for (int n = 0; n < 2; ++n)
      #pragma unroll
      for (int j = 0; j < 4; ++j) {
        int row = m0 + m * 16 + ((lane >> 4) << 2) + j;
        int col = n0 + wc * 32 + n * 16 + (lane & 15);
        out[(size_t)row * 1024 + col] = acc[m][n][j] + bias[col];
      }
}

// ---------- causal flash attention: LDS-free, barrier-free ----------
// Swapped-QK^T body (round-5/9-verified fragment algebra); every MFMA fragment
// is a contiguous 16B global slice: K A-frag from K[key][d] rows, V B-frag from
// V^T[d][q] rows. K software-prefetched one tile ahead; V issued at tile start.
// No LDS, no __syncthreads, 4 independent waves per block.
__device__ __forceinline__ void attn_one(
    const u16* __restrict__ Qh, const u16* __restrict__ Kh, const u16* __restrict__ VTh,
    u16* __restrict__ Ob, int bb, int h, int qt) {
  const int tid = threadIdx.x, lane = tid & 63, w = tid >> 6;
  const int g = lane >> 4, q15 = lane & 15;
  const int qrow = qt * 64 + w * 16 + q15;

  // Q fragment (B-operand): lane holds Q[qrow][kk*32 + 8g + i]
  bf16x8 qf[2];
  #pragma unroll
  for (int kk = 0; kk < 2; ++kk)
    qf[kk] = *(const bf16x8*)(Qh + (size_t)qrow * 64 + kk * 32 + g * 8);

  f32x4 acc_o[4];
  #pragma unroll
  for (int n = 0; n < 4; ++n) acc_o[n] = (f32x4){0.f, 0.f, 0.f, 0.f};
  float m_run = -INFINITY, l_run = 0.f;

  const int nt = qt + 1;

  // K fragments for tile 0
  bf16x8 kc[4][2];
  #pragma unroll
  for (int cb = 0; cb < 4; ++cb)
    #pragma unroll
    for (int kk = 0; kk < 2; ++kk)
      kc[cb][kk] = *(const bf16x8*)(Kh + (size_t)(cb * 16 + q15) * 64 + kk * 32 + g * 8);

  for (int t = 0; t < nt; ++t) {
    // prefetch next K tile fragments (hidden under softmax+PV of tile t)
    bf16x8 kn[4][2];
    if (t + 1 < nt) {
      #pragma unroll
      for (int cb = 0; cb < 4; ++cb)
        #pragma unroll
        for (int kk = 0; kk < 2; ++kk)
          kn[cb][kk] = *(const bf16x8*)(Kh +
              (size_t)((t + 1) * 64 + cb * 16 + q15) * 64 + kk * 32 + g * 8);
    }
    // V fragments for tile t (drain under QK^T + softmax)
    bf16x8 vf[4][2];
    #pragma unroll
    for (int n = 0; n < 4; ++n)
      #pragma unroll
      for (int kk = 0; kk < 2; ++kk)
        vf[n][kk] = *(const bf16x8*)(VTh +
            (size_t)(n * 16 + q15) * 2048 + t * 64 + kk * 32 + g * 8);

    // ---- ST = K @ Q^T : lane holds P[q=q15][key = 16cb + 4g + j] ----
    f32x4 accs[4];
    __builtin_amdgcn_s_setprio(1);
    #pragma unroll
    for (int cb = 0; cb < 4; ++cb) {
      accs[cb] = (f32x4){0.f, 0.f, 0.f, 0.f};
      #pragma unroll
      for (int kk = 0; kk < 2; ++kk)
        accs[cb] = MFMA16(kc[cb][kk], qf[kk], accs[cb]);
    }
    __builtin_amdgcn_s_setprio(0);

    // causal mask on diagonal tile
    if (t == nt - 1) {
      #pragma unroll
      for (int cb = 0; cb < 4; ++cb)
        #pragma unroll
        for (int j = 0; j < 4; ++j) {
          int kg = t * 64 + cb * 16 + 4 * g + j;
          if (kg > qrow) accs[cb][j] = -INFINITY;
        }
    }

    // ---- online softmax (exp2 domain), lane-local q-row ----
    float mj = accs[0][0];
    #pragma unroll
    for (int cb = 0; cb < 4; ++cb)
      #pragma unroll
      for (int j = 0; j < 4; ++j) mj = fmaxf(mj, accs[cb][j]);
    mj = fmaxf(mj, __shfl_xor(mj, 16));
    mj = fmaxf(mj, __shfl_xor(mj, 32));
    float mn = fmaxf(m_run, mj);
    float sc = exp2f(m_run - mn);
    m_run = mn;
    float rs = 0.f;
    #pragma unroll
    for (int cb = 0; cb < 4; ++cb)
      #pragma unroll
      for (int j = 0; j < 4; ++j) {
        float p = exp2f(accs[cb][j] - mn);
        accs[cb][j] = p;
        rs += p;
      }
    rs += __shfl_xor(rs, 16);
    rs += __shfl_xor(rs, 32);
    l_run = l_run * sc + rs;

    // rescale acc_o (its rows live at q-local = 4g+j)
    float scj[4];
    #pragma unroll
    for (int j = 0; j < 4; ++j) scj[j] = __shfl(sc, 4 * g + j);
    #pragma unroll
    for (int n = 0; n < 4; ++n)
      #pragma unroll
      for (int j = 0; j < 4; ++j) acc_o[n][j] *= scj[j];

    // ---- pack P to bf16 pairs: Wp[cb][hh] = keys (16cb+4g+2hh, +1) ----
    unsigned Wp[4][2];
    #pragma unroll
    for (int cb = 0; cb < 4; ++cb)
      #pragma unroll
      for (int hh = 0; hh < 2; ++hh)
        asm("v_cvt_pk_bf16_f32 %0, %1, %2"
            : "=v"(Wp[cb][hh]) : "v"(accs[cb][2 * hh]), "v"(accs[cb][2 * hh + 1]));

    // ---- exchange into PV A-fragments: lane needs keys kk*32+8g..+7 ----
    unsigned aw[2][4];
    #pragma unroll
    for (int kk = 0; kk < 2; ++kk)
      #pragma unroll
      for (int iw = 0; iw < 4; ++iw) {
        int srcLane = q15 + ((((g & 1) << 1) + (iw >> 1)) << 4);
        unsigned c0 = __shfl(Wp[2 * kk + 0][iw & 1], srcLane);
        unsigned c1 = __shfl(Wp[2 * kk + 1][iw & 1], srcLane);
        aw[kk][iw] = (g >> 1) ? c1 : c0;
      }
    bf16x8 pa0 = __builtin_bit_cast(bf16x8, (u32x4){aw[0][0], aw[0][1], aw[0][2], aw[0][3]});
    bf16x8 pa1 = __builtin_bit_cast(bf16x8, (u32x4){aw[1][0], aw[1][1], aw[1][2], aw[1][3]});

    // ---- O += P @ V ----
    __builtin_amdgcn_s_setprio(1);
    #pragma unroll
    for (int n = 0; n < 4; ++n) {
      acc_o[n] = MFMA16(pa0, vf[n][0], acc_o[n]);
      acc_o[n] = MFMA16(pa1, vf[n][1], acc_o[n]);
    }
    __builtin_amdgcn_s_setprio(0);

    // rotate K prefetch
    if (t + 1 < nt) {
      #pragma unroll
      for (int cb = 0; cb < 4; ++cb)
        #pragma unroll
        for (int kk = 0; kk < 2; ++kk)
          kc[cb][kk] = kn[cb][kk];
    }
  }

  // ---- epilogue: O /= l, write bf16 to [B*C, H] ----
  float invl = 1.0f / l_run;
  float invj[4];
  #pragma unroll
  for (int j = 0; j < 4; ++j) invj[j] = __shfl(invl, 4 * g + j);
  #pragma unroll
  for (int n = 0; n < 4; ++n)
    #pragma unroll
    for (int j = 0; j < 4; ++j) {
      int qg = qt * 64 + w * 16 + 4 * g + j;
      Ob[((size_t)(bb * 2048 + qg)) * 1024 + h * 64 + n * 16 + q15] =
          f2bf(acc_o[n][j] * invj[j]);
    }
}

// grid = 32 heads x 16 balanced pairs; block handles q-tiles (31-p, p): 33 KV tiles.
__global__ __launch_bounds__(256, 2) void attn_kernel(
    const u16* __restrict__ Qb, const u16* __restrict__ Kb, const u16* __restrict__ VTb,
    u16* __restrict__ Ob) {
  const int blk = blockIdx.x;
  const int p = blk & 15;
  const int bh = blk >> 4;             // 0..31 (b*16+h)
  const size_t base = (size_t)bh * 2048 * 64;   // same for K and V^T
  const int bb = bh >> 4, h = bh & 15;
  attn_one(Qb + base, Kb + base, VTb + base, Ob, bb, h, 31 - p);
  attn_one(Qb + base, Kb + base, VTb + base, Ob, bb, h, p);
}

// ---------- launch ----------
extern "C" void kernel_launch(void* const* d_in, const int* in_sizes, int n_in,
                              void* d_out, int out_size, void* d_ws, size_t ws_size,
                              hipStream_t stream) {
  const float* x    = (const float*)d_in[0];   // [2,2048,1024]
  const float* wqkv = (const float*)d_in[1];   // [3072,1024]
  const float* bqkv = (const float*)d_in[2];   // [3072]
  const float* wo   = (const float*)d_in[3];   // [1024,1024]
  const float* bo   = (const float*)d_in[4];   // [1024]
  float* out = (float*)d_out;                  // [4096,1024] fp32

  const size_t MB = 1u << 20;
  char* ws = (char*)d_ws;
  u16* x_bf  = (u16*)(ws);             // 8 MB
  u16* wq_bf = (u16*)(ws + 8 * MB);    // 6 MB
  u16* wo_bf = (u16*)(ws + 14 * MB);   // 2 MB
  u16* q_buf = (u16*)(ws + 16 * MB);   // 8 MB  [B,nh,C,64]
  u16* k_buf = (u16*)(ws + 24 * MB);   // 8 MB  [B,nh,C,64]
  u16* vt_buf= (u16*)(ws + 32 * MB);   // 8 MB  [B,nh,64,C]  (transposed)
  u16* a_out = (u16*)(ws + 40 * MB);   // 8 MB  [4096,1024]

  cast_all_kernel<<<8192, 256, 0, stream>>>(x, wqkv, wo, x_bf, wq_bf, wo_bf);

  gemm_qkv_kernel<<<dim3(24, 32), 256, 0, stream>>>(x_bf, wq_bf, bqkv,
                                                    q_buf, k_buf, vt_buf);
  attn_kernel<<<512, 256, 0, stream>>>(q_buf, k_buf, vt_buf, a_out);
  gemm_out_kernel<<<dim3(8, 64), 256, 0, stream>>>(a_out, wo_bf, bo, out);
}

// Round 11
// 151.177 us; speedup vs baseline: 1.4235x; 1.4235x over previous
//
#include <hip/hip_runtime.h>
#include <hip/hip_bf16.h>
#include <math.h>

typedef unsigned short u16;
typedef __attribute__((ext_vector_type(8))) __bf16 bf16x8;
typedef __attribute__((ext_vector_type(4))) float f32x4;
typedef __attribute__((ext_vector_type(8))) unsigned short u16x8;
typedef __attribute__((ext_vector_type(4))) unsigned int u32x4;

// ---------- helpers ----------
__device__ __forceinline__ u16 f2bf(float f) {
  union { float f; unsigned u; } x; x.f = f;
  unsigned r = x.u + 0x7fffu + ((x.u >> 16) & 1u);   // RNE
  return (u16)(r >> 16);
}

__device__ __forceinline__ void gload16(const u16* g, u16* l) {
  __builtin_amdgcn_global_load_lds(
      (const __attribute__((address_space(1))) void*)g,
      (__attribute__((address_space(3))) void*)l, 16, 0, 0);
}

#define MFMA16(a, b, c) __builtin_amdgcn_mfma_f32_16x16x32_bf16((a), (b), (c), 0, 0, 0)

// Q pre-scale: 1/sqrt(64) * log2(e)  (softmax done in exp2 domain)
#define QSCALE 0.18033688011112043f

// ---------- merged cast fp32 -> bf16 (x, Wqkv, Wo in one launch) ----------
__global__ __launch_bounds__(256) void cast_all_kernel(
    const float* __restrict__ x, const float* __restrict__ wqkv,
    const float* __restrict__ wo, u16* __restrict__ xb,
    u16* __restrict__ wqb, u16* __restrict__ wob) {
  int i = blockIdx.x * 256 + threadIdx.x;   // in float4 units
  const float* src; u16* dst;
  if (i < 1048576)      { src = x;    dst = xb;  }
  else if (i < 1835008) { src = wqkv; dst = wqb; i -= 1048576; }
  else                  { src = wo;   dst = wob; i -= 1835008; }
  f32x4 v = *(const f32x4*)(src + (size_t)i * 4);
  u16 o0 = f2bf(v[0]), o1 = f2bf(v[1]), o2 = f2bf(v[2]), o3 = f2bf(v[3]);
  unsigned lo = (unsigned)o0 | ((unsigned)o1 << 16);
  unsigned hi = (unsigned)o2 | ((unsigned)o3 << 16);
  ((unsigned*)dst)[(size_t)i * 2] = lo;
  ((unsigned*)dst)[(size_t)i * 2 + 1] = hi;
}

// ---------- shared 128x128 / BK=64 bf16 GEMM main loop (C = A * B^T) ----------
__device__ __forceinline__ void gemm_bt_128(
    const u16* __restrict__ A, const u16* __restrict__ B, int K, int m0, int n0,
    u16* As, u16* Bs, f32x4 acc[4][4]) {
  const int tid = threadIdx.x;
  const int lane = tid & 63;
  const int wr = tid >> 7;
  const int wc = (tid >> 6) & 1;
  for (int k0 = 0; k0 < K; k0 += 64) {
    #pragma unroll
    for (int it = 0; it < 4; ++it) {
      int c = it * 256 + tid;
      int row = c >> 3;
      int ko = (c & 7) << 3;
      gload16(A + (size_t)(m0 + row) * K + (k0 + ko), As + c * 8);
      gload16(B + (size_t)(n0 + row) * K + (k0 + ko), Bs + c * 8);
    }
    __syncthreads();
    #pragma unroll
    for (int kk = 0; kk < 2; ++kk) {
      bf16x8 a[4], b[4];
      #pragma unroll
      for (int m = 0; m < 4; ++m)
        a[m] = *(const bf16x8*)(As + ((wr * 64 + m * 16 + (lane & 15)) * 64 +
                                      kk * 32 + ((lane >> 4) << 3)));
      #pragma unroll
      for (int n = 0; n < 4; ++n)
        b[n] = *(const bf16x8*)(Bs + ((wc * 64 + n * 16 + (lane & 15)) * 64 +
                                      kk * 32 + ((lane >> 4) << 3)));
      #pragma unroll
      for (int m = 0; m < 4; ++m)
        #pragma unroll
        for (int n = 0; n < 4; ++n)
          acc[m][n] = MFMA16(a[m], b[n], acc[m][n]);
    }
    __syncthreads();
  }
}

// ---------- GEMM1: qkv = x @ Wqkv^T + b, scatter q/k/v to [B,nh,C,64] bf16 ----------
__global__ __launch_bounds__(256) void gemm_qkv_kernel(
    const u16* __restrict__ X, const u16* __restrict__ W, const float* __restrict__ bias,
    u16* __restrict__ Qb, u16* __restrict__ Kb, u16* __restrict__ Vb) {
  __shared__ __align__(16) u16 As[128 * 64];
  __shared__ __align__(16) u16 Bs[128 * 64];
  f32x4 acc[4][4];
  #pragma unroll
  for (int m = 0; m < 4; ++m)
    #pragma unroll
    for (int n = 0; n < 4; ++n) acc[m][n] = (f32x4){0.f, 0.f, 0.f, 0.f};
  const int m0 = blockIdx.y * 128;
  const int n0 = blockIdx.x * 128;
  gemm_bt_128(X, W, 1024, m0, n0, As, Bs, acc);
  const int lane = threadIdx.x & 63;
  const int wr = threadIdx.x >> 7, wc = (threadIdx.x >> 6) & 1;
  #pragma unroll
  for (int m = 0; m < 4; ++m) {
    #pragma unroll
    for (int n = 0; n < 4; ++n) {
      #pragma unroll
      for (int j = 0; j < 4; ++j) {
        int row = m0 + wr * 64 + m * 16 + ((lane >> 4) << 2) + j;
        int col = n0 + wc * 64 + n * 16 + (lane & 15);
        float v = acc[m][n][j] + bias[col];
        int which = col >> 10;
        int rem = col & 1023;
        int h = rem >> 6, d = rem & 63;
        int bb = row >> 11, q = row & 2047;
        if (which == 0) v *= QSCALE;  // Q pre-scale (exp2-domain softmax)
        u16* dst = (which == 0) ? Qb : (which == 1 ? Kb : Vb);
        dst[((size_t)((bb * 16 + h) * 2048 + q)) * 64 + d] = f2bf(v);
      }
    }
  }
}

// ---------- GEMM2: out = attn @ Wo^T + b (fp32 out), 64x128 tile ----------
__global__ __launch_bounds__(256) void gemm_out_kernel(
    const u16* __restrict__ Ain, const u16* __restrict__ W, const float* __restrict__ bias,
    float* __restrict__ out) {
  __shared__ __align__(16) u16 As[64 * 64];
  __shared__ __align__(16) u16 Bs[128 * 64];
  const int tid = threadIdx.x;
  const int lane = tid & 63;
  const int wc = tid >> 6;                 // wave -> 32-col group
  const int m0 = blockIdx.y * 64;
  const int n0 = blockIdx.x * 128;
  f32x4 acc[4][2] = {};
  for (int k0 = 0; k0 < 1024; k0 += 64) {
    #pragma unroll
    for (int it = 0; it < 2; ++it) {
      int c = it * 256 + tid;
      gload16(Ain + (size_t)(m0 + (c >> 3)) * 1024 + k0 + ((c & 7) << 3), As + c * 8);
    }
    #pragma unroll
    for (int it = 0; it < 4; ++it) {
      int c = it * 256 + tid;
      gload16(W + (size_t)(n0 + (c >> 3)) * 1024 + k0 + ((c & 7) << 3), Bs + c * 8);
    }
    __syncthreads();
    #pragma unroll
    for (int kk = 0; kk < 2; ++kk) {
      bf16x8 a[4], b[2];
      #pragma unroll
      for (int m = 0; m < 4; ++m)
        a[m] = *(const bf16x8*)(As + ((m * 16 + (lane & 15)) * 64 +
                                      kk * 32 + ((lane >> 4) << 3)));
      #pragma unroll
      for (int n = 0; n < 2; ++n)
        b[n] = *(const bf16x8*)(Bs + ((wc * 32 + n * 16 + (lane & 15)) * 64 +
                                      kk * 32 + ((lane >> 4) << 3)));
      #pragma unroll
      for (int m = 0; m < 4; ++m)
        #pragma unroll
        for (int n = 0; n < 2; ++n)
          acc[m][n] = MFMA16(a[m], b[n], acc[m][n]);
    }
    __syncthreads();
  }
  #pragma unroll
  for (int m = 0; m < 4; ++m)
    #pragma unroll
    for (int n = 0; n < 2; ++n)
      #pragma unroll
      for (int j = 0; j < 4; ++j) {
        int row = m0 + m * 16 + ((lane >> 4) << 2) + j;
        int col = n0 + wc * 32 + n * 16 + (lane & 15);
        out[(size_t)row * 1024 + col] = acc[m][n][j] + bias[col];
      }
}

// ---------- causal flash attention: swapped-QK^T, in-register softmax & P ----------
// r9-verified body + T4 counted-vmcnt: 3-deep LDS ring, stage t+2 while reading
// tile t; end-of-tile wait = vmcnt(6) (this tile's 4 K-gloads + 2 V-reg loads
// stay in flight), vmcnt(0) only when no prefetch was issued. Raw s_barrier.
__device__ __forceinline__ void attn_one(
    const u16* __restrict__ Qh, const u16* __restrict__ Kh, const u16* __restrict__ Vh,
    u16* __restrict__ Ob, int bb, int h, int qt,
    u16 (*Ks)[64 * 64], u16 (*Vt)[64 * 64]) {
  const int tid = threadIdx.x, lane = tid & 63, w = tid >> 6;
  const int g = lane >> 4, q15 = lane & 15;

  // Q fragment (B-operand): lane holds Q[qrow][kk*32 + 8g + i]
  bf16x8 qf[2];
  const int qrow = qt * 64 + w * 16 + q15;
  #pragma unroll
  for (int kk = 0; kk < 2; ++kk)
    qf[kk] = *(const bf16x8*)(Qh + (size_t)qrow * 64 + kk * 32 + g * 8);

  f32x4 acc_o[4];
  #pragma unroll
  for (int n = 0; n < 4; ++n) acc_o[n] = (f32x4){0.f, 0.f, 0.f, 0.f};
  float m_run = -INFINITY, l_run = 0.f;

  const int nt = qt + 1;

  auto stageK = [&](int t, int buf) {    // 4 gload16 per thread (K tile t)
    #pragma unroll
    for (int it = 0; it < 2; ++it) {
      int c = it * 256 + tid;
      int row = c >> 3, b8 = c & 7;
      gload16(Kh + (size_t)(t * 64 + row) * 64 + ((b8 ^ (row & 7)) << 3),
              Ks[buf] + c * 8);
    }
  };
  auto loadV = [&](int t, u16x8 vreg[2]) {   // 2 global vector loads per thread
    #pragma unroll
    for (int it = 0; it < 2; ++it) {
      int kloc = it * 32 + (tid >> 3);
      int d0 = (tid & 7) << 3;
      vreg[it] = *(const u16x8*)(Vh + (size_t)(t * 64 + kloc) * 64 + d0);
    }
  };
  auto writeV = [&](const u16x8 vreg[2], int buf) {  // transposed swizzled ds_write
    #pragma unroll
    for (int it = 0; it < 2; ++it) {
      int kloc = it * 32 + (tid >> 3);
      int d0 = (tid & 7) << 3;
      #pragma unroll
      for (int i = 0; i < 8; ++i) {
        int d = d0 + i;
        int fv = (d + (d >> 3)) & 7;
        Vt[buf][d * 64 + (((kloc >> 3) ^ fv) << 3) + (kloc & 7)] = vreg[it][i];
      }
    }
  };

  // ---- prologue: K(0)->buf0, V(0)->LDS buf0; K(1)->buf1, V(1)->regs ----
  u16x8 vcur[2];
  {
    stageK(0, 0);
    u16x8 v0[2];
    loadV(0, v0);
    if (nt > 1) { stageK(1, 1); loadV(1, vcur); }
    writeV(v0, 0);
    if (nt > 1) asm volatile("s_waitcnt vmcnt(6) lgkmcnt(0)\ns_barrier" ::: "memory");
    else        asm volatile("s_waitcnt vmcnt(0) lgkmcnt(0)\ns_barrier" ::: "memory");
  }

  int b0 = 0, b1 = 1, b2 = 2;
  for (int t = 0; t < nt; ++t) {
    const bool pre2 = (t + 2 < nt);
    const bool pre1 = (t + 1 < nt);
    u16x8 vnext[2];
    if (pre2) { stageK(t + 2, b2); loadV(t + 2, vnext); }

    // ---- ST = K @ Q^T : lane holds P[q=q15][key = 16cb + 4g + j] ----
    f32x4 accs[4];
    __builtin_amdgcn_s_setprio(1);
    #pragma unroll
    for (int cb = 0; cb < 4; ++cb) {
      accs[cb] = (f32x4){0.f, 0.f, 0.f, 0.f};
      #pragma unroll
      for (int kk = 0; kk < 2; ++kk) {
        int row = cb * 16 + q15;
        int kblk = kk * 4 + g;
        bf16x8 kf = *(const bf16x8*)(Ks[b0] + row * 64 + ((kblk ^ (row & 7)) << 3));
        accs[cb] = MFMA16(kf, qf[kk], accs[cb]);
      }
    }
    __builtin_amdgcn_s_setprio(0);
    // causal mask on diagonal tile
    if (t == nt - 1) {
      #pragma unroll
      for (int cb = 0; cb < 4; ++cb)
        #pragma unroll
        for (int j = 0; j < 4; ++j) {
          int kg = t * 64 + cb * 16 + 4 * g + j;
          if (kg > qrow) accs[cb][j] = -INFINITY;
        }
    }

    // ---- online softmax (exp2 domain), lane-local q-row ----
    float mj = accs[0][0];
    #pragma unroll
    for (int cb = 0; cb < 4; ++cb)
      #pragma unroll
      for (int j = 0; j < 4; ++j) mj = fmaxf(mj, accs[cb][j]);
    mj = fmaxf(mj, __shfl_xor(mj, 16));
    mj = fmaxf(mj, __shfl_xor(mj, 32));
    float mn = fmaxf(m_run, mj);
    float sc = exp2f(m_run - mn);
    m_run = mn;
    float rs = 0.f;
    #pragma unroll
    for (int cb = 0; cb < 4; ++cb)
      #pragma unroll
      for (int j = 0; j < 4; ++j) {
        float p = exp2f(accs[cb][j] - mn);
        accs[cb][j] = p;
        rs += p;
      }
    rs += __shfl_xor(rs, 16);
    rs += __shfl_xor(rs, 32);
    l_run = l_run * sc + rs;

    // rescale acc_o (its rows live at q-local = 4g+j)
    float scj[4];
    #pragma unroll
    for (int j = 0; j < 4; ++j) scj[j] = __shfl(sc, 4 * g + j);
    #pragma unroll
    for (int n = 0; n < 4; ++n)
      #pragma unroll
      for (int j = 0; j < 4; ++j) acc_o[n][j] *= scj[j];

    // ---- pack P to bf16 pairs: Wp[cb][hh] = keys (16cb+4g+2hh, +1) ----
    unsigned Wp[4][2];
    #pragma unroll
    for (int cb = 0; cb < 4; ++cb)
      #pragma unroll
      for (int hh = 0; hh < 2; ++hh)
        asm("v_cvt_pk_bf16_f32 %0, %1, %2"
            : "=v"(Wp[cb][hh]) : "v"(accs[cb][2 * hh]), "v"(accs[cb][2 * hh + 1]));

    // ---- exchange into PV A-fragments: lane needs keys kk*32+8g..+7 ----
    unsigned aw[2][4];
    #pragma unroll
    for (int kk = 0; kk < 2; ++kk)
      #pragma unroll
      for (int iw = 0; iw < 4; ++iw) {
        int srcLane = q15 + ((((g & 1) << 1) + (iw >> 1)) << 4);
        unsigned c0 = __shfl(Wp[2 * kk + 0][iw & 1], srcLane);
        unsigned c1 = __shfl(Wp[2 * kk + 1][iw & 1], srcLane);
        aw[kk][iw] = (g >> 1) ? c1 : c0;
      }
    bf16x8 pa0 = __builtin_bit_cast(bf16x8, (u32x4){aw[0][0], aw[0][1], aw[0][2], aw[0][3]});
    bf16x8 pa1 = __builtin_bit_cast(bf16x8, (u32x4){aw[1][0], aw[1][1], aw[1][2], aw[1][3]});

    // ---- O += P @ V  (V via swizzled ds_read_b128) ----
    __builtin_amdgcn_s_setprio(1);
    #pragma unroll
    for (int n = 0; n < 4; ++n) {
      #pragma unroll
      for (int kk = 0; kk < 2; ++kk) {
        int cblk = kk * 4 + g;
        int d = n * 16 + q15;
        int fv = (d + (d >> 3)) & 7;
        bf16x8 vb = *(const bf16x8*)(Vt[b0] + d * 64 + ((cblk ^ fv) << 3));
        acc_o[n] = MFMA16(kk ? pa1 : pa0, vb, acc_o[n]);
      }
    }
    __builtin_amdgcn_s_setprio(0);

    // write-late: V(t+1) regs -> LDS buf b1, then rotate held regs
    if (pre1) {
      writeV(vcur, b1);
      if (pre2) { vcur[0] = vnext[0]; vcur[1] = vnext[1]; }
    }

    // counted-vmcnt barrier: t+2's 6 loads stay in flight
    if (pre2) asm volatile("s_waitcnt vmcnt(6) lgkmcnt(0)\ns_barrier" ::: "memory");
    else      asm volatile("s_waitcnt vmcnt(0) lgkmcnt(0)\ns_barrier" ::: "memory");

    int tmp = b0; b0 = b1; b1 = b2; b2 = tmp;
  }

  // ---- epilogue: O /= l, write bf16 to [B*C, H] ----
  float invl = 1.0f / l_run;
  float invj[4];
  #pragma unroll
  for (int j = 0; j < 4; ++j) invj[j] = __shfl(invl, 4 * g + j);
  #pragma unroll
  for (int n = 0; n < 4; ++n)
    #pragma unroll
    for (int j = 0; j < 4; ++j) {
      int qg = qt * 64 + w * 16 + 4 * g + j;
      Ob[((size_t)(bb * 2048 + qg)) * 1024 + h * 64 + n * 16 + q15] =
          f2bf(acc_o[n][j] * invj[j]);
    }
}

// grid = 32 heads x 16 balanced pairs; block handles q-tiles (31-p, p): 33 KV tiles.
__global__ __launch_bounds__(256, 4) void attn_kernel(
    const u16* __restrict__ Qb, const u16* __restrict__ Kb, const u16* __restrict__ Vb,
    u16* __restrict__ Ob) {
  __shared__ __align__(16) u16 Ks[3][64 * 64];
  __shared__ __align__(16) u16 Vt[3][64 * 64];
  const int blk = blockIdx.x;
  const int p = blk & 15;
  const int bh = blk >> 4;             // 0..31 (b*16+h)
  const size_t base = (size_t)bh * 2048 * 64;
  const int bb = bh >> 4, h = bh & 15;
  attn_one(Qb + base, Kb + base, Vb + base, Ob, bb, h, 31 - p, Ks, Vt);
  attn_one(Qb + base, Kb + base, Vb + base, Ob, bb, h, p, Ks, Vt);
}

// ---------- launch ----------
extern "C" void kernel_launch(void* const* d_in, const int* in_sizes, int n_in,
                              void* d_out, int out_size, void* d_ws, size_t ws_size,
                              hipStream_t stream) {
  const float* x    = (const float*)d_in[0];   // [2,2048,1024]
  const float* wqkv = (const float*)d_in[1];   // [3072,1024]
  const float* bqkv = (const float*)d_in[2];   // [3072]
  const float* wo   = (const float*)d_in[3];   // [1024,1024]
  const float* bo   = (const float*)d_in[4];   // [1024]
  float* out = (float*)d_out;                  // [4096,1024] fp32

  const size_t MB = 1u << 20;
  char* ws = (char*)d_ws;
  u16* x_bf  = (u16*)(ws);             // 8 MB
  u16* wq_bf = (u16*)(ws + 8 * MB);    // 6 MB
  u16* wo_bf = (u16*)(ws + 14 * MB);   // 2 MB
  u16* q_buf = (u16*)(ws + 16 * MB);   // 8 MB  [B,nh,C,64]
  u16* k_buf = (u16*)(ws + 24 * MB);   // 8 MB
  u16* v_buf = (u16*)(ws + 32 * MB);   // 8 MB
  u16* a_out = (u16*)(ws + 40 * MB);   // 8 MB  [4096,1024]

  cast_all_kernel<<<8192, 256, 0, stream>>>(x, wqkv, wo, x_bf, wq_bf, wo_bf);

  gemm_qkv_kernel<<<dim3(24, 32), 256, 0, stream>>>(x_bf, wq_bf, bqkv,
                                                    q_buf, k_buf, v_buf);
  attn_kernel<<<512, 256, 0, stream>>>(q_buf, k_buf, v_buf, a_out);
  gemm_out_kernel<<<dim3(8, 64), 256, 0, stream>>>(a_out, wo_bf, bo, out);
}

// Round 12
// 147.706 us; speedup vs baseline: 1.4569x; 1.0235x over previous
//
#include <hip/hip_runtime.h>
#include <hip/hip_bf16.h>
#include <math.h>

typedef unsigned short u16;
typedef __attribute__((ext_vector_type(8))) __bf16 bf16x8;
typedef __attribute__((ext_vector_type(4))) float f32x4;
typedef __attribute__((ext_vector_type(8))) unsigned short u16x8;
typedef __attribute__((ext_vector_type(4))) unsigned int u32x4;

// ---------- helpers ----------
__device__ __forceinline__ u16 f2bf(float f) {
  union { float f; unsigned u; } x; x.f = f;
  unsigned r = x.u + 0x7fffu + ((x.u >> 16) & 1u);   // RNE
  return (u16)(r >> 16);
}

__device__ __forceinline__ void gload16(const u16* g, u16* l) {
  __builtin_amdgcn_global_load_lds(
      (const __attribute__((address_space(1))) void*)g,
      (__attribute__((address_space(3))) void*)l, 16, 0, 0);
}

#define MFMA16(a, b, c) __builtin_amdgcn_mfma_f32_16x16x32_bf16((a), (b), (c), 0, 0, 0)

// Q pre-scale: 1/sqrt(64) * log2(e)  (softmax done in exp2 domain)
#define QSCALE 0.18033688011112043f

// ---------- merged cast fp32 -> bf16 (x, Wqkv, Wo in one launch) ----------
__global__ __launch_bounds__(256) void cast_all_kernel(
    const float* __restrict__ x, const float* __restrict__ wqkv,
    const float* __restrict__ wo, u16* __restrict__ xb,
    u16* __restrict__ wqb, u16* __restrict__ wob) {
  int i = blockIdx.x * 256 + threadIdx.x;   // in float4 units
  const float* src; u16* dst;
  if (i < 1048576)      { src = x;    dst = xb;  }
  else if (i < 1835008) { src = wqkv; dst = wqb; i -= 1048576; }
  else                  { src = wo;   dst = wob; i -= 1835008; }
  f32x4 v = *(const f32x4*)(src + (size_t)i * 4);
  u16 o0 = f2bf(v[0]), o1 = f2bf(v[1]), o2 = f2bf(v[2]), o3 = f2bf(v[3]);
  unsigned lo = (unsigned)o0 | ((unsigned)o1 << 16);
  unsigned hi = (unsigned)o2 | ((unsigned)o3 << 16);
  ((unsigned*)dst)[(size_t)i * 2] = lo;
  ((unsigned*)dst)[(size_t)i * 2 + 1] = hi;
}

// ---------- shared 128x128 / BK=64 bf16 GEMM main loop (C = A * B^T) ----------
__device__ __forceinline__ void gemm_bt_128(
    const u16* __restrict__ A, const u16* __restrict__ B, int K, int m0, int n0,
    u16* As, u16* Bs, f32x4 acc[4][4]) {
  const int tid = threadIdx.x;
  const int lane = tid & 63;
  const int wr = tid >> 7;
  const int wc = (tid >> 6) & 1;
  for (int k0 = 0; k0 < K; k0 += 64) {
    #pragma unroll
    for (int it = 0; it < 4; ++it) {
      int c = it * 256 + tid;
      int row = c >> 3;
      int ko = (c & 7) << 3;
      gload16(A + (size_t)(m0 + row) * K + (k0 + ko), As + c * 8);
      gload16(B + (size_t)(n0 + row) * K + (k0 + ko), Bs + c * 8);
    }
    __syncthreads();
    #pragma unroll
    for (int kk = 0; kk < 2; ++kk) {
      bf16x8 a[4], b[4];
      #pragma unroll
      for (int m = 0; m < 4; ++m)
        a[m] = *(const bf16x8*)(As + ((wr * 64 + m * 16 + (lane & 15)) * 64 +
                                      kk * 32 + ((lane >> 4) << 3)));
      #pragma unroll
      for (int n = 0; n < 4; ++n)
        b[n] = *(const bf16x8*)(Bs + ((wc * 64 + n * 16 + (lane & 15)) * 64 +
                                      kk * 32 + ((lane >> 4) << 3)));
      #pragma unroll
      for (int m = 0; m < 4; ++m)
        #pragma unroll
        for (int n = 0; n < 4; ++n)
          acc[m][n] = MFMA16(a[m], b[n], acc[m][n]);
    }
    __syncthreads();
  }
}

// ---------- GEMM1: qkv = x @ Wqkv^T + b, scatter q/k/v to [B,nh,C,64] bf16 ----------
// Epilogue through LDS: stage bf16 C-tile (stride 136, 16B-aligned rows), then
// cooperative u16x8 stores (two contiguous 128B segments per 16 lanes).
__global__ __launch_bounds__(256) void gemm_qkv_kernel(
    const u16* __restrict__ X, const u16* __restrict__ W, const float* __restrict__ bias,
    u16* __restrict__ Qb, u16* __restrict__ Kb, u16* __restrict__ Vb) {
  __shared__ __align__(16) u16 S[17408];   // 2x 128x64 staging, reused as 128x136 C
  f32x4 acc[4][4];
  #pragma unroll
  for (int m = 0; m < 4; ++m)
    #pragma unroll
    for (int n = 0; n < 4; ++n) acc[m][n] = (f32x4){0.f, 0.f, 0.f, 0.f};
  const int m0 = blockIdx.y * 128;
  const int n0 = blockIdx.x * 128;
  gemm_bt_128(X, W, 1024, m0, n0, S, S + 8192, acc);

  const int tid = threadIdx.x;
  const int lane = tid & 63;
  const int wr = tid >> 7, wc = (tid >> 6) & 1;
  const int which = n0 >> 10;                       // 0=Q 1=K 2=V (block-uniform)
  const float qs = (which == 0) ? QSCALE : 1.0f;
  u16* __restrict__ dst = (which == 0) ? Qb : (which == 1 ? Kb : Vb);

  // stage C-tile (bias + scale applied) into LDS
  #pragma unroll
  for (int m = 0; m < 4; ++m)
    #pragma unroll
    for (int n = 0; n < 4; ++n)
      #pragma unroll
      for (int j = 0; j < 4; ++j) {
        int row = wr * 64 + m * 16 + ((lane >> 4) << 2) + j;
        int col = wc * 64 + n * 16 + (lane & 15);
        float v = (acc[m][n][j] + bias[n0 + col]) * qs;
        S[row * 136 + col] = f2bf(v);
      }
  __syncthreads();

  // vectorized store: 2048 16B-chunks, 8 per thread
  #pragma unroll
  for (int i = 0; i < 8; ++i) {
    int c = i * 256 + tid;
    int row = c >> 4, ch = c & 15;
    u16x8 val = *(const u16x8*)(S + row * 136 + ch * 8);
    int grow = m0 + row;
    int bb = grow >> 11, q = grow & 2047;
    int gcol = n0 + ch * 8;
    int h = (gcol >> 6) & 15, d0 = gcol & 63;
    *(u16x8*)(dst + ((size_t)((bb * 16 + h) * 2048 + q)) * 64 + d0) = val;
  }
}

// ---------- GEMM2: out = attn @ Wo^T + b (fp32 out), 64x128 tile ----------
__global__ __launch_bounds__(256) void gemm_out_kernel(
    const u16* __restrict__ Ain, const u16* __restrict__ W, const float* __restrict__ bias,
    float* __restrict__ out) {
  __shared__ __align__(16) u16 As[64 * 64];
  __shared__ __align__(16) u16 Bs[128 * 64];
  const int tid = threadIdx.x;
  const int lane = tid & 63;
  const int wc = tid >> 6;                 // wave -> 32-col group
  const int m0 = blockIdx.y * 64;
  const int n0 = blockIdx.x * 128;
  f32x4 acc[4][2] = {};
  for (int k0 = 0; k0 < 1024; k0 += 64) {
    #pragma unroll
    for (int it = 0; it < 2; ++it) {
      int c = it * 256 + tid;
      gload16(Ain + (size_t)(m0 + (c >> 3)) * 1024 + k0 + ((c & 7) << 3), As + c * 8);
    }
    #pragma unroll
    for (int it = 0; it < 4; ++it) {
      int c = it * 256 + tid;
      gload16(W + (size_t)(n0 + (c >> 3)) * 1024 + k0 + ((c & 7) << 3), Bs + c * 8);
    }
    __syncthreads();
    #pragma unroll
    for (int kk = 0; kk < 2; ++kk) {
      bf16x8 a[4], b[2];
      #pragma unroll
      for (int m = 0; m < 4; ++m)
        a[m] = *(const bf16x8*)(As + ((m * 16 + (lane & 15)) * 64 +
                                      kk * 32 + ((lane >> 4) << 3)));
      #pragma unroll
      for (int n = 0; n < 2; ++n)
        b[n] = *(const bf16x8*)(Bs + ((wc * 32 + n * 16 + (lane & 15)) * 64 +
                                      kk * 32 + ((lane >> 4) << 3)));
      #pragma unroll
      for (int m = 0; m < 4; ++m)
        #pragma unroll
        for (int n = 0; n < 2; ++n)
          acc[m][n] = MFMA16(a[m], b[n], acc[m][n]);
    }
    __syncthreads();
  }
  #pragma unroll
  for (int m = 0; m < 4; ++m)
    #pragma unroll
    for (int n = 0; n < 2; ++n)
      #pragma unroll
      for (int j = 0; j < 4; ++j) {
        int row = m0 + m * 16 + ((lane >> 4) << 2) + j;
        int col = n0 + wc * 32 + n * 16 + (lane & 15);
        out[(size_t)row * 1024 + col] = acc[m][n][j] + bias[col];
      }
}

// ---------- causal flash attention: swapped-QK^T, in-register softmax & P ----------
// r9-verified body + T13 defer-max (skip O-rescale while max growth <= 8 in
// exp2 domain; P bounded by 2^8, fp32 accum absorbs it).
__device__ __forceinline__ void attn_one(
    const u16* __restrict__ Qh, const u16* __restrict__ Kh, const u16* __restrict__ Vh,
    u16* __restrict__ Ob, int bb, int h, int qt,
    u16 (*Ks)[64 * 64], u16 (*Vt)[64 * 64]) {
  const int tid = threadIdx.x, lane = tid & 63, w = tid >> 6;
  const int g = lane >> 4, q15 = lane & 15;

  // Q fragment (B-operand): lane holds Q[qrow][kk*32 + 8g + i]
  bf16x8 qf[2];
  const int qrow = qt * 64 + w * 16 + q15;
  #pragma unroll
  for (int kk = 0; kk < 2; ++kk)
    qf[kk] = *(const bf16x8*)(Qh + (size_t)qrow * 64 + kk * 32 + g * 8);

  f32x4 acc_o[4];
  #pragma unroll
  for (int n = 0; n < 4; ++n) acc_o[n] = (f32x4){0.f, 0.f, 0.f, 0.f};
  float m_run = -INFINITY, l_run = 0.f;

  const int nt = qt + 1;

  auto stageK = [&](int t, int buf) {
    #pragma unroll
    for (int it = 0; it < 2; ++it) {
      int c = it * 256 + tid;
      int row = c >> 3, b8 = c & 7;
      gload16(Kh + (size_t)(t * 64 + row) * 64 + ((b8 ^ (row & 7)) << 3),
              Ks[buf] + c * 8);
    }
  };

  // ---- prologue: tile 0 ----
  stageK(0, 0);
  #pragma unroll
  for (int it = 0; it < 2; ++it) {
    int kloc = it * 32 + (tid >> 3);
    int d0 = (tid & 7) << 3;
    u16x8 v = *(const u16x8*)(Vh + (size_t)kloc * 64 + d0);
    #pragma unroll
    for (int i = 0; i < 8; ++i) {
      int d = d0 + i;
      int fv = (d + (d >> 3)) & 7;
      Vt[0][d * 64 + (((kloc >> 3) ^ fv) << 3) + (kloc & 7)] = v[i];
    }
  }
  __syncthreads();

  for (int t = 0; t < nt; ++t) {
    const int cur = t & 1;
    const bool pre = (t + 1 < nt);
    u16x8 vreg[2];
    if (pre) {
      stageK(t + 1, cur ^ 1);
      #pragma unroll
      for (int it = 0; it < 2; ++it) {
        int kloc = it * 32 + (tid >> 3);
        int d0 = (tid & 7) << 3;
        vreg[it] = *(const u16x8*)(Vh + (size_t)((t + 1) * 64 + kloc) * 64 + d0);
      }
    }

    // ---- ST = K @ Q^T : lane holds P[q=q15][key = 16cb + 4g + j] ----
    f32x4 accs[4];
    __builtin_amdgcn_s_setprio(1);
    #pragma unroll
    for (int cb = 0; cb < 4; ++cb) {
      accs[cb] = (f32x4){0.f, 0.f, 0.f, 0.f};
      #pragma unroll
      for (int kk = 0; kk < 2; ++kk) {
        int row = cb * 16 + q15;
        int kblk = kk * 4 + g;
        bf16x8 kf = *(const bf16x8*)(Ks[cur] + row * 64 + ((kblk ^ (row & 7)) << 3));
        accs[cb] = MFMA16(kf, qf[kk], accs[cb]);
      }
    }
    __builtin_amdgcn_s_setprio(0);
    // causal mask on diagonal tile
    if (t == nt - 1) {
      #pragma unroll
      for (int cb = 0; cb < 4; ++cb)
        #pragma unroll
        for (int j = 0; j < 4; ++j) {
          int kg = t * 64 + cb * 16 + 4 * g + j;
          if (kg > qrow) accs[cb][j] = -INFINITY;
        }
    }

    // ---- online softmax (exp2 domain), lane-local q-row, T13 defer-max ----
    float mj = accs[0][0];
    #pragma unroll
    for (int cb = 0; cb < 4; ++cb)
      #pragma unroll
      for (int j = 0; j < 4; ++j) mj = fmaxf(mj, accs[cb][j]);
    mj = fmaxf(mj, __shfl_xor(mj, 16));
    mj = fmaxf(mj, __shfl_xor(mj, 32));
    if (!__all(mj - m_run <= 8.0f)) {
      float mn = fmaxf(m_run, mj);
      float sc = exp2f(m_run - mn);
      m_run = mn;
      l_run *= sc;
      float scj[4];
      #pragma unroll
      for (int j = 0; j < 4; ++j) scj[j] = __shfl(sc, 4 * g + j);
      #pragma unroll
      for (int n = 0; n < 4; ++n)
        #pragma unroll
        for (int j = 0; j < 4; ++j) acc_o[n][j] *= scj[j];
    }
    float rs = 0.f;
    #pragma unroll
    for (int cb = 0; cb < 4; ++cb)
      #pragma unroll
      for (int j = 0; j < 4; ++j) {
        float p = exp2f(accs[cb][j] - m_run);
        accs[cb][j] = p;
        rs += p;
      }
    rs += __shfl_xor(rs, 16);
    rs += __shfl_xor(rs, 32);
    l_run += rs;

    // ---- pack P to bf16 pairs: Wp[cb][hh] = keys (16cb+4g+2hh, +1) ----
    unsigned Wp[4][2];
    #pragma unroll
    for (int cb = 0; cb < 4; ++cb)
      #pragma unroll
      for (int hh = 0; hh < 2; ++hh)
        asm("v_cvt_pk_bf16_f32 %0, %1, %2"
            : "=v"(Wp[cb][hh]) : "v"(accs[cb][2 * hh]), "v"(accs[cb][2 * hh + 1]));

    // ---- exchange into PV A-fragments: lane needs keys kk*32+8g..+7 ----
    unsigned aw[2][4];
    #pragma unroll
    for (int kk = 0; kk < 2; ++kk)
      #pragma unroll
      for (int iw = 0; iw < 4; ++iw) {
        int srcLane = q15 + ((((g & 1) << 1) + (iw >> 1)) << 4);
        unsigned c0 = __shfl(Wp[2 * kk + 0][iw & 1], srcLane);
        unsigned c1 = __shfl(Wp[2 * kk + 1][iw & 1], srcLane);
        aw[kk][iw] = (g >> 1) ? c1 : c0;
      }
    bf16x8 pa0 = __builtin_bit_cast(bf16x8, (u32x4){aw[0][0], aw[0][1], aw[0][2], aw[0][3]});
    bf16x8 pa1 = __builtin_bit_cast(bf16x8, (u32x4){aw[1][0], aw[1][1], aw[1][2], aw[1][3]});

    // ---- O += P @ V  (V via swizzled ds_read_b128) ----
    __builtin_amdgcn_s_setprio(1);
    #pragma unroll
    for (int n = 0; n < 4; ++n) {
      #pragma unroll
      for (int kk = 0; kk < 2; ++kk) {
        int cblk = kk * 4 + g;
        int d = n * 16 + q15;
        int fv = (d + (d >> 3)) & 7;
        bf16x8 vb = *(const bf16x8*)(Vt[cur] + d * 64 + ((cblk ^ fv) << 3));
        acc_o[n] = MFMA16(kk ? pa1 : pa0, vb, acc_o[n]);
      }
    }
    __builtin_amdgcn_s_setprio(0);

    if (pre) {
      // write-late: V regs -> LDS (swizzled) after compute
      #pragma unroll
      for (int it = 0; it < 2; ++it) {
        int kloc = it * 32 + (tid >> 3);
        int d0 = (tid & 7) << 3;
        #pragma unroll
        for (int i = 0; i < 8; ++i) {
          int d = d0 + i;
          int fv = (d + (d >> 3)) & 7;
          Vt[cur ^ 1][d * 64 + (((kloc >> 3) ^ fv) << 3) + (kloc & 7)] = vreg[it][i];
        }
      }
    }
    __syncthreads();
  }

  // ---- epilogue: O /= l, write bf16 to [B*C, H] ----
  float invl = 1.0f / l_run;
  float invj[4];
  #pragma unroll
  for (int j = 0; j < 4; ++j) invj[j] = __shfl(invl, 4 * g + j);
  #pragma unroll
  for (int n = 0; n < 4; ++n)
    #pragma unroll
    for (int j = 0; j < 4; ++j) {
      int qg = qt * 64 + w * 16 + 4 * g + j;
      Ob[((size_t)(bb * 2048 + qg)) * 1024 + h * 64 + n * 16 + q15] =
          f2bf(acc_o[n][j] * invj[j]);
    }
}

// grid = 32 heads x 16 balanced pairs; block handles q-tiles (31-p, p): 33 KV tiles.
__global__ __launch_bounds__(256, 4) void attn_kernel(
    const u16* __restrict__ Qb, const u16* __restrict__ Kb, const u16* __restrict__ Vb,
    u16* __restrict__ Ob) {
  __shared__ __align__(16) u16 Ks[2][64 * 64];
  __shared__ __align__(16) u16 Vt[2][64 * 64];
  const int blk = blockIdx.x;
  const int p = blk & 15;
  const int bh = blk >> 4;             // 0..31 (b*16+h)
  const size_t base = (size_t)bh * 2048 * 64;
  const int bb = bh >> 4, h = bh & 15;
  attn_one(Qb + base, Kb + base, Vb + base, Ob, bb, h, 31 - p, Ks, Vt);
  attn_one(Qb + base, Kb + base, Vb + base, Ob, bb, h, p, Ks, Vt);
}

// ---------- launch ----------
extern "C" void kernel_launch(void* const* d_in, const int* in_sizes, int n_in,
                              void* d_out, int out_size, void* d_ws, size_t ws_size,
                              hipStream_t stream) {
  const float* x    = (const float*)d_in[0];   // [2,2048,1024]
  const float* wqkv = (const float*)d_in[1];   // [3072,1024]
  const float* bqkv = (const float*)d_in[2];   // [3072]
  const float* wo   = (const float*)d_in[3];   // [1024,1024]
  const float* bo   = (const float*)d_in[4];   // [1024]
  float* out = (float*)d_out;                  // [4096,1024] fp32

  const size_t MB = 1u << 20;
  char* ws = (char*)d_ws;
  u16* x_bf  = (u16*)(ws);             // 8 MB
  u16* wq_bf = (u16*)(ws + 8 * MB);    // 6 MB
  u16* wo_bf = (u16*)(ws + 14 * MB);   // 2 MB
  u16* q_buf = (u16*)(ws + 16 * MB);   // 8 MB  [B,nh,C,64]
  u16* k_buf = (u16*)(ws + 24 * MB);   // 8 MB
  u16* v_buf = (u16*)(ws + 32 * MB);   // 8 MB
  u16* a_out = (u16*)(ws + 40 * MB);   // 8 MB  [4096,1024]

  cast_all_kernel<<<8192, 256, 0, stream>>>(x, wqkv, wo, x_bf, wq_bf, wo_bf);

  gemm_qkv_kernel<<<dim3(24, 32), 256, 0, stream>>>(x_bf, wq_bf, bqkv,
                                                    q_buf, k_buf, v_buf);
  attn_kernel<<<512, 256, 0, stream>>>(q_buf, k_buf, v_buf, a_out);
  gemm_out_kernel<<<dim3(8, 64), 256, 0, stream>>>(a_out, wo_bf, bo, out);
}